// Round 18
// baseline (252.207 us; speedup 1.0000x reference)
//
#include <hip/hip_runtime.h>

typedef __attribute__((ext_vector_type(8))) short bf16x8;
typedef __attribute__((ext_vector_type(16))) float f32x16;
typedef _Float16 f16;
typedef __attribute__((ext_vector_type(8))) _Float16 f16x8;

static __device__ __forceinline__ unsigned short f2bf(float x) {
  unsigned int u = __float_as_uint(x);
  return (unsigned short)((u + 0x7FFFu + ((u >> 16) & 1u)) >> 16);
}
static __device__ __forceinline__ unsigned int pk2bf(float lo, float hi) {
  return ((unsigned int)f2bf(hi) << 16) | f2bf(lo);
}
static __device__ __forceinline__ f16x8 relu8(f16x8 x) {
  f16x8 z = {0, 0, 0, 0, 0, 0, 0, 0};
  return __builtin_elementwise_max(x, z);
}

// ================= fused prep: tobf (blocks 0..255), w2h (256..511), uvh (512..767) =================
__global__ __launch_bounds__(256) void prep_kernel(const float* __restrict__ states,
                                                   const float* __restrict__ Wi2,
                                                   const float* __restrict__ Wi1,
                                                   const float* __restrict__ bi1,
                                                   unsigned short* __restrict__ Sbf,
                                                   f16* __restrict__ W2h,
                                                   f16* __restrict__ Uh, f16* __restrict__ Vh) {
  __shared__ float lds_f[1536];
  const int t = threadIdx.x;
  const int bid = blockIdx.x;
  if (bid < 256) {
    const int idx = bid * 256 + t;
    float4 v = ((const float4*)states)[idx];
    ushort4 o;
    o.x = f2bf(v.x); o.y = f2bf(v.y); o.z = f2bf(v.z); o.w = f2bf(v.w);
    ((ushort4*)Sbf)[idx] = o;
  } else if (bid < 512) {
    const int b = bid - 256;
    const int bk = b & 15, bn = b >> 4;
    float (*tile)[33] = (float(*)[33])lds_f;
    const int r = t >> 5, c = t & 31;
#pragma unroll
    for (int p = 0; p < 4; p++) {
      int rr = p * 8 + r;
      tile[rr][c] = Wi2[(bk * 32 + rr) * 512 + bn * 32 + c];
    }
    __syncthreads();
#pragma unroll
    for (int p = 0; p < 4; p++) {
      int rr = p * 8 + r;
      W2h[(bn * 32 + rr) * 512 + bk * 32 + c] = (f16)tile[c][rr];
    }
  } else {
    const int row0 = (bid - 512) * 8;
    float (*st)[12] = (float(*)[12])lds_f;
    for (int idx = t; idx < 1024; idx += 256) {
      int r = idx >> 7, k = idx & 127;
      st[k][r] = states[(row0 + r) * 128 + k];
    }
    __syncthreads();
    float au0[8], au1[8], av0[8], av1[8];
#pragma unroll
    for (int r = 0; r < 8; r++) { au0[r] = 0.f; au1[r] = 0.f; av0[r] = 0.f; av1[r] = 0.f; }
#pragma unroll 4
    for (int k = 0; k < 128; k++) {
      float wt0 = Wi1[k * 512 + t];
      float wt1 = Wi1[k * 512 + 256 + t];
      float wb0 = Wi1[(k + 128) * 512 + t];
      float wb1 = Wi1[(k + 128) * 512 + 256 + t];
      float4 sA = *(const float4*)&st[k][0];
      float4 sB = *(const float4*)&st[k][4];
      float s8[8] = {sA.x, sA.y, sA.z, sA.w, sB.x, sB.y, sB.z, sB.w};
#pragma unroll
      for (int r = 0; r < 8; r++) {
        au0[r] += s8[r] * wt0;
        au1[r] += s8[r] * wt1;
        av0[r] += s8[r] * wb0;
        av1[r] += s8[r] * wb1;
      }
    }
    const float b0 = bi1[t], b1 = bi1[256 + t];
#pragma unroll
    for (int r = 0; r < 8; r++) {
      Uh[(row0 + r) * 512 + t]       = (f16)(au0[r] + b0);
      Uh[(row0 + r) * 512 + 256 + t] = (f16)(au1[r] + b1);
      Vh[(row0 + r) * 512 + t]       = (f16)av0[r];
      Vh[(row0 + r) * 512 + 256 + t] = (f16)av1[r];
    }
  }
}

// ---------------- MFMA M=32 weight-streaming GEMM (R15 2-bank body, LDS sized by LT) ----------------
// LT = k-slice length; LDS A-tile = 64*LT bytes. launch_bounds(256,8): 8 waves/EU, VGPR<=64.
template <int LT>
__global__ __launch_bounds__(256, 8) void gemmw_t(const unsigned short* __restrict__ Abf,
                                                  const float* __restrict__ W,
                                                  float* __restrict__ P,
                                                  int K, int N) {
  constexpr int L4 = LT >> 2;
  constexpr int L4SH = (LT == 512) ? 7 : (LT == 256) ? 6 : (LT == 128) ? 5 : (LT == 64) ? 4 : 2;
  constexpr int SWZM = 2 * LT - 1;
  __shared__ __align__(16) unsigned short As[32 * LT];
  const int t = threadIdx.x;
  const int k0 = blockIdx.y * LT;
  for (int idx = t; idx < (LT << 3); idx += 256) {
    int row = idx >> L4SH, k4 = idx & (L4 - 1);
    ushort4 a4 = *(const ushort4*)&Abf[(size_t)row * K + k0 + k4 * 4];
    int off = (row * 2 * LT + k4 * 8) ^ (((row & 7) << 4) & SWZM);
    *(ushort4*)((char*)As + off) = a4;
  }
  __syncthreads();
  const int lane = t & 63, w = t >> 6;
  const int lrow = lane & 31, lh = lane >> 5;
  const int col = blockIdx.x * 128 + w * 32 + lrow;
  f32x16 acc0, acc1;
#pragma unroll
  for (int r = 0; r < 16; r++) { acc0[r] = 0.f; acc1[r] = 0.f; }
  const float* Wp = W + (size_t)(k0 + lh * 8) * N + col;
  const int aswz = ((lrow & 7) << 4) & SWZM;
  const int abase = lrow * 2 * LT + lh * 16;
  constexpr int NKS = LT >> 4;
  int ks = 0;
  for (; ks + 1 < NKS; ks += 2) {
    float wv0[8], wv1[8];
#pragma unroll
    for (int jj = 0; jj < 8; jj++) wv0[jj] = Wp[(size_t)(ks * 16 + jj) * N];
#pragma unroll
    for (int jj = 0; jj < 8; jj++) wv1[jj] = Wp[(size_t)(ks * 16 + 16 + jj) * N];
    uint4 b0, b1;
    b0.x = pk2bf(wv0[0], wv0[1]); b0.y = pk2bf(wv0[2], wv0[3]);
    b0.z = pk2bf(wv0[4], wv0[5]); b0.w = pk2bf(wv0[6], wv0[7]);
    b1.x = pk2bf(wv1[0], wv1[1]); b1.y = pk2bf(wv1[2], wv1[3]);
    b1.z = pk2bf(wv1[4], wv1[5]); b1.w = pk2bf(wv1[6], wv1[7]);
    bf16x8 af0 = *(const bf16x8*)((const char*)As + ((abase + ks * 32) ^ aswz));
    bf16x8 af1 = *(const bf16x8*)((const char*)As + ((abase + ks * 32 + 32) ^ aswz));
    acc0 = __builtin_amdgcn_mfma_f32_32x32x16_bf16(af0, *(const bf16x8*)&b0, acc0, 0, 0, 0);
    acc1 = __builtin_amdgcn_mfma_f32_32x32x16_bf16(af1, *(const bf16x8*)&b1, acc1, 0, 0, 0);
  }
  if (ks < NKS) {
    float wv0[8];
#pragma unroll
    for (int jj = 0; jj < 8; jj++) wv0[jj] = Wp[(size_t)(ks * 16 + jj) * N];
    uint4 b0;
    b0.x = pk2bf(wv0[0], wv0[1]); b0.y = pk2bf(wv0[2], wv0[3]);
    b0.z = pk2bf(wv0[4], wv0[5]); b0.w = pk2bf(wv0[6], wv0[7]);
    bf16x8 af0 = *(const bf16x8*)((const char*)As + ((abase + ks * 32) ^ aswz));
    acc0 = __builtin_amdgcn_mfma_f32_32x32x16_bf16(af0, *(const bf16x8*)&b0, acc0, 0, 0, 0);
  }
  float* Pr = P + (size_t)blockIdx.y * 32 * N + col;
#pragma unroll
  for (int r = 0; r < 16; r++) {
    int row = (r & 3) + 8 * (r >> 2) + 4 * lh;
    Pr[(size_t)row * N] = acc0[r] + acc1[r];
  }
}

// ================= reduce partials + bias + act (+ bf16 copy) (+ fused final combine) =================
__global__ __launch_bounds__(256) void reduce_kernel(const float* __restrict__ P,
                                                     const float* __restrict__ bias,
                                                     float* __restrict__ dst,
                                                     unsigned short* __restrict__ dstbf,
                                                     int lnN, int KS, int act, int wbf,
                                                     const float* __restrict__ S,
                                                     const float* __restrict__ Ip,
                                                     float* __restrict__ out0, int comb) {
  const int idx = blockIdx.x * 256 + threadIdx.x;
  const int N = 1 << lnN;
  const int m = idx >> lnN, n = idx & (N - 1);
  float s = 0.f;
#pragma unroll 8
  for (int p = 0; p < KS; p++) s += P[((size_t)(p * 32 + m) << lnN) + n];
  s += bias[n];
  if (act == 1) s = fmaxf(s, 0.f);
  else if (act == 2) s = tanhf(s);
  dst[idx] = s;
  if (wbf) dstbf[idx] = f2bf(s);
  if (comb) out0[idx] = S[idx] + 0.1f * (Ip[idx] + s);
}

// ================= interaction core v6 (R9-proven): V via LDS, persistent-B =================
__global__ __launch_bounds__(512, 2) void inter6_kernel(const f16* __restrict__ Uh,
                                                        const f16* __restrict__ Vh,
                                                        const f16* __restrict__ W2h,
                                                        const float* __restrict__ bi2,
                                                        float* __restrict__ Hsum) {
  __shared__ __align__(16) f16 Bt[128 * 512]; // 128KB
  __shared__ __align__(16) f16 Vc[64 * 128];  // 16KB
  const int t = threadIdx.x;
  const int nq = blockIdx.x;

#pragma unroll
  for (int i = 0; i < 16; i++) {
    int idx = i * 512 + t;
    int n = idx >> 6, ch = idx & 63;
    f16x8 w8 = *(const f16x8*)&W2h[(size_t)(nq * 128 + n) * 512 + ch * 8];
    int off = (n * 1024 + ch * 16) ^ ((n & 15) << 4);
    *(f16x8*)((char*)Bt + off) = w8;
  }

  const int w = t >> 6, lane = t & 63;
  const int ii = w & 1, tg = w >> 1;
  const int lrow = lane & 31, lh = lane >> 5;
  const char* Btc = (const char*)Bt;
  const char* Vcc = (const char*)Vc;
  char* Vcw = (char*)Vc;

  int bofs[4], bswz[4];
#pragma unroll
  for (int nf = 0; nf < 4; nf++) {
    int nr = nf * 32 + lrow;
    bofs[nf] = nr * 1024 + lh * 16;
    bswz[nf] = (nr & 15) << 4;
  }
  const int vofs0 = lrow * 256;
  const int vswz0 = (lrow & 15) << 4;
  const int vofs1 = (lrow + 32) * 256;
  const int vswz1 = vswz0;

  const int b = blockIdx.y >> 1;

  for (int s = 0; s < 4; s++) {
    const int tid = blockIdx.y * 16 + tg * 4 + s;
    const int it = tid & 31;
    const f16* Ub = Uh + (size_t)(b * 64 + it * 2 + ii) * 512 + lh * 8;

    f32x16 acc[2][4];
#pragma unroll
    for (int mf = 0; mf < 2; mf++)
#pragma unroll
      for (int nf = 0; nf < 4; nf++)
#pragma unroll
        for (int r = 0; r < 16; r++) acc[mf][nf][r] = 0.f;

    for (int ch = 0; ch < 4; ch++) {
      const int kc = ch * 128;
      __syncthreads();
#pragma unroll
      for (int i = 0; i < 2; i++) {
        int idx = i * 512 + t;
        int row = idx >> 4, c8 = idx & 15;
        f16x8 w8 = *(const f16x8*)&Vh[(size_t)(b * 64 + row) * 512 + kc + c8 * 8];
        *(f16x8*)(Vcw + ((row * 256 + c8 * 16) ^ ((row & 15) << 4))) = w8;
      }
      __syncthreads();
#pragma unroll
      for (int k16 = 0; k16 < 8; k16++) {
        const int kb2 = k16 * 32 + lh * 16;
        f16x8 v0 = *(const f16x8*)(Vcc + ((vofs0 + kb2) ^ vswz0));
        f16x8 v1 = *(const f16x8*)(Vcc + ((vofs1 + kb2) ^ vswz1));
        f16x8 u0 = *(const f16x8*)(Ub + kc + k16 * 16);
        f16x8 a0 = relu8(v0 + u0);
        f16x8 a1 = relu8(v1 + u0);
#pragma unroll
        for (int nf = 0; nf < 4; nf++) {
          f16x8 bfr = *(const f16x8*)(Btc + ((bofs[nf] + (kc + k16 * 16) * 2) ^ bswz[nf]));
          acc[0][nf] = __builtin_amdgcn_mfma_f32_32x32x16_f16(a0, bfr, acc[0][nf], 0, 0, 0);
          acc[1][nf] = __builtin_amdgcn_mfma_f32_32x32x16_f16(a1, bfr, acc[1][nf], 0, 0, 0);
        }
      }
    }

    const int iglob = it * 2 + ii;
    const int mf_d = iglob >> 5;
    const int rd = iglob & 31;
    const int lh_d = (rd >> 2) & 1;
    const int r_d = (rd & 3) + 4 * (rd >> 3);
#pragma unroll
    for (int nf = 0; nf < 4; nf++) {
      const int col = nq * 128 + nf * 32 + lrow;
      const float b2 = bi2[col];
      float ssum = 0.f;
#pragma unroll
      for (int mf = 0; mf < 2; mf++)
#pragma unroll
        for (int r = 0; r < 16; r++) {
          float x = fmaxf(acc[mf][nf][r] + b2, 0.f);
          if (mf == mf_d && r == r_d && lh == lh_d) x = 0.f;
          ssum += x;
        }
      ssum += __shfl_xor(ssum, 32);
      if (lh == 0) Hsum[(size_t)(b * 64 + iglob) * 512 + col] = ssum;
    }
  }
}

// ---------------- interactions = (Hsum/63) @ Wi3 + bi3, 256 blocks ----------------
__global__ __launch_bounds__(256) void k3_kernel(const float* __restrict__ Hsum,
                                                 const float* __restrict__ Wi3,
                                                 const float* __restrict__ bi3,
                                                 float* __restrict__ inter) {
  __shared__ float st[512][10];
  const int t = threadIdx.x;
  const int row0 = blockIdx.x * 8;
  for (int idx = t; idx < 4096; idx += 256) {
    int r = idx >> 9, k = idx & 511;
    st[k][r] = Hsum[(row0 + r) * 512 + k] * (1.0f / 63.0f);
  }
  __syncthreads();
  const int c = t & 63;
  const int rg = t >> 6;
  float a0[2] = {0.f, 0.f}, a1[2] = {0.f, 0.f};
#pragma unroll 4
  for (int k = 0; k < 512; k++) {
    float w0 = Wi3[k * 128 + c];
    float w1 = Wi3[k * 128 + 64 + c];
    float2 h = *(const float2*)&st[k][rg * 2];
    a0[0] += h.x * w0; a0[1] += h.y * w0;
    a1[0] += h.x * w1; a1[1] += h.y * w1;
  }
  float b0 = bi3[c], b1 = bi3[64 + c];
#pragma unroll
  for (int r = 0; r < 2; r++) {
    inter[(row0 + rg * 2 + r) * 128 + c]      = a0[r] + b0;
    inter[(row0 + rg * 2 + r) * 128 + 64 + c] = a1[r] + b1;
  }
}

extern "C" void kernel_launch(void* const* d_in, const int* in_sizes, int n_in,
                              void* d_out, int out_size, void* d_ws, size_t ws_size,
                              hipStream_t stream) {
  const float* states = (const float*)d_in[0];
  const float* Wq  = (const float*)d_in[2];
  const float* bq  = (const float*)d_in[3];
  const float* Wi1 = (const float*)d_in[4];
  const float* bi1 = (const float*)d_in[5];
  const float* Wi2 = (const float*)d_in[6];
  const float* bi2 = (const float*)d_in[7];
  const float* Wi3 = (const float*)d_in[8];
  const float* bi3 = (const float*)d_in[9];
  const float* Wc1 = (const float*)d_in[10];
  const float* bc1 = (const float*)d_in[11];
  const float* Wc2 = (const float*)d_in[12];
  const float* bc2 = (const float*)d_in[13];
  const float* Wc3 = (const float*)d_in[14];
  const float* bc3 = (const float*)d_in[15];

  float* out   = (float*)d_out;
  float* out0  = out;            // coordinated_states (B,A,D)
  float* qf    = out + 262144;   // quantum_features (B,F)
  float* inter = out + 524288;   // interactions (B,A,D)
  float* coord = out + 786432;   // coordination (B,A,D)

  char* ws = (char*)d_ws;
  float*          P    = (float*)(ws);                                   // 32MB partials (KS=32 max)
  f16*            Uh   = (f16*)(ws + ((size_t)33 << 20));                // 2MB
  f16*            Vh   = (f16*)(ws + ((size_t)36 << 20));                // 2MB
  f16*            W2h  = (f16*)(ws + ((size_t)39 << 20));                // 0.5MB
  float*          Hsum = (float*)(ws + ((size_t)40 << 20));              // 4MB
  unsigned short* Sbf  = (unsigned short*)(ws + ((size_t)44 << 20));     // 0.5MB
  unsigned short* qfbf = (unsigned short*)(ws + ((size_t)45 << 20));     // 0.5MB
  float*          c1   = (float*)(ws + ((size_t)46 << 20));              // 64KB
  float*          c2   = (float*)(ws + ((size_t)46 << 20) + (1 << 16));  // 64KB
  unsigned short* c1bf = (unsigned short*)(ws + ((size_t)46 << 20) + (2 << 16)); // 32KB
  unsigned short* c2bf = (unsigned short*)(ws + ((size_t)46 << 20) + (3 << 16)); // 32KB

  // fused prep: tobf + w2h + uvh
  prep_kernel<<<768, 256, 0, stream>>>(states, Wi2, Wi1, bi1, Sbf, W2h, Uh, Vh);

  // quantum features: qf = tanh(states @ Wq + bq) — L=256, KS=32, 8 blocks/CU occupancy
  gemmw_t<256><<<dim3(64, 32), 256, 0, stream>>>(Sbf, Wq, P, 8192, 8192);
  reduce_kernel<<<1024, 256, 0, stream>>>(P, bq, qf, qfbf, 13, 32, 2, 1,
                                          nullptr, nullptr, nullptr, 0);

  // interactions
  inter6_kernel<<<dim3(4, 64), 512, 0, stream>>>(Uh, Vh, W2h, bi2, Hsum);
  k3_kernel<<<256, 256, 0, stream>>>(Hsum, Wi3, bi3, inter);

  // coordination chain
  gemmw_t<128><<<dim3(4, 64), 256, 0, stream>>>(qfbf, Wc1, P, 8192, 512);
  reduce_kernel<<<64, 256, 0, stream>>>(P, bc1, c1, c1bf, 9, 64, 1, 1,
                                        nullptr, nullptr, nullptr, 0);
  gemmw_t<16><<<dim3(4, 32), 256, 0, stream>>>(c1bf, Wc2, P, 512, 512);
  reduce_kernel<<<64, 256, 0, stream>>>(P, bc2, c2, c2bf, 9, 32, 1, 1,
                                        nullptr, nullptr, nullptr, 0);

  // coord = c2 @ Wc3 + bc3 + fused final combine
  gemmw_t<64><<<dim3(64, 8), 256, 0, stream>>>(c2bf, Wc3, P, 512, 8192);
  reduce_kernel<<<1024, 256, 0, stream>>>(P, bc3, coord, nullptr, 13, 8, 0, 0,
                                          states, inter, out0, 1);
}

// Round 19
// 219.390 us; speedup vs baseline: 1.1496x; 1.1496x over previous
//
#include <hip/hip_runtime.h>

typedef __attribute__((ext_vector_type(8))) short bf16x8;
typedef __attribute__((ext_vector_type(16))) float f32x16;
typedef _Float16 f16;
typedef __attribute__((ext_vector_type(8))) _Float16 f16x8;

static __device__ __forceinline__ unsigned short f2bf(float x) {
  unsigned int u = __float_as_uint(x);
  return (unsigned short)((u + 0x7FFFu + ((u >> 16) & 1u)) >> 16);
}
static __device__ __forceinline__ unsigned int pk2bf(float lo, float hi) {
  return ((unsigned int)f2bf(hi) << 16) | f2bf(lo);
}
static __device__ __forceinline__ f16x8 relu8(f16x8 x) {
  f16x8 z = {0, 0, 0, 0, 0, 0, 0, 0};
  return __builtin_elementwise_max(x, z);
}

// ================= fused prep: tobf (blocks 0..255), w2h (256..511), uvh (512..767) =================
__global__ __launch_bounds__(256) void prep_kernel(const float* __restrict__ states,
                                                   const float* __restrict__ Wi2,
                                                   const float* __restrict__ Wi1,
                                                   const float* __restrict__ bi1,
                                                   unsigned short* __restrict__ Sbf,
                                                   f16* __restrict__ W2h,
                                                   f16* __restrict__ Uh, f16* __restrict__ Vh) {
  __shared__ float lds_f[1536];
  const int t = threadIdx.x;
  const int bid = blockIdx.x;
  if (bid < 256) {
    const int idx = bid * 256 + t;
    float4 v = ((const float4*)states)[idx];
    ushort4 o;
    o.x = f2bf(v.x); o.y = f2bf(v.y); o.z = f2bf(v.z); o.w = f2bf(v.w);
    ((ushort4*)Sbf)[idx] = o;
  } else if (bid < 512) {
    const int b = bid - 256;
    const int bk = b & 15, bn = b >> 4;
    float (*tile)[33] = (float(*)[33])lds_f;
    const int r = t >> 5, c = t & 31;
#pragma unroll
    for (int p = 0; p < 4; p++) {
      int rr = p * 8 + r;
      tile[rr][c] = Wi2[(bk * 32 + rr) * 512 + bn * 32 + c];
    }
    __syncthreads();
#pragma unroll
    for (int p = 0; p < 4; p++) {
      int rr = p * 8 + r;
      W2h[(bn * 32 + rr) * 512 + bk * 32 + c] = (f16)tile[c][rr];
    }
  } else {
    const int row0 = (bid - 512) * 8;
    float (*st)[12] = (float(*)[12])lds_f;
    for (int idx = t; idx < 1024; idx += 256) {
      int r = idx >> 7, k = idx & 127;
      st[k][r] = states[(row0 + r) * 128 + k];
    }
    __syncthreads();
    float au0[8], au1[8], av0[8], av1[8];
#pragma unroll
    for (int r = 0; r < 8; r++) { au0[r] = 0.f; au1[r] = 0.f; av0[r] = 0.f; av1[r] = 0.f; }
#pragma unroll 4
    for (int k = 0; k < 128; k++) {
      float wt0 = Wi1[k * 512 + t];
      float wt1 = Wi1[k * 512 + 256 + t];
      float wb0 = Wi1[(k + 128) * 512 + t];
      float wb1 = Wi1[(k + 128) * 512 + 256 + t];
      float4 sA = *(const float4*)&st[k][0];
      float4 sB = *(const float4*)&st[k][4];
      float s8[8] = {sA.x, sA.y, sA.z, sA.w, sB.x, sB.y, sB.z, sB.w};
#pragma unroll
      for (int r = 0; r < 8; r++) {
        au0[r] += s8[r] * wt0;
        au1[r] += s8[r] * wt1;
        av0[r] += s8[r] * wb0;
        av1[r] += s8[r] * wb1;
      }
    }
    const float b0 = bi1[t], b1 = bi1[256 + t];
#pragma unroll
    for (int r = 0; r < 8; r++) {
      Uh[(row0 + r) * 512 + t]       = (f16)(au0[r] + b0);
      Uh[(row0 + r) * 512 + 256 + t] = (f16)(au1[r] + b1);
      Vh[(row0 + r) * 512 + t]       = (f16)av0[r];
      Vh[(row0 + r) * 512 + 256 + t] = (f16)av1[r];
    }
  }
}

// ---------------- MFMA M=32 weight-streaming GEMM (R9/R13-proven 2-bank body) ----------------
__global__ __launch_bounds__(256, 4) void gemmw(const unsigned short* __restrict__ Abf,
                                                const float* __restrict__ W,
                                                float* __restrict__ P,
                                                int K, int N, int L, int l4sh) {
  __shared__ __align__(16) unsigned short As[32 * 512];
  const int t = threadIdx.x;
  const int k0 = blockIdx.y * L;
  const int L4 = L >> 2;
  const int swzm = 2 * L - 1;
  for (int idx = t; idx < (L << 3); idx += 256) {
    int row = idx >> l4sh, k4 = idx & (L4 - 1);
    ushort4 a4 = *(const ushort4*)&Abf[(size_t)row * K + k0 + k4 * 4];
    int off = (row * 2 * L + k4 * 8) ^ (((row & 7) << 4) & swzm);
    *(ushort4*)((char*)As + off) = a4;
  }
  __syncthreads();
  const int lane = t & 63, w = t >> 6;
  const int lrow = lane & 31, lh = lane >> 5;
  const int col = blockIdx.x * 128 + w * 32 + lrow;
  f32x16 acc0, acc1;
#pragma unroll
  for (int r = 0; r < 16; r++) { acc0[r] = 0.f; acc1[r] = 0.f; }
  const float* Wp = W + (size_t)(k0 + lh * 8) * N + col;
  const int aswz = ((lrow & 7) << 4) & swzm;
  const int abase = lrow * 2 * L + lh * 16;
  const int nks = L >> 4;
  int ks = 0;
  for (; ks + 1 < nks; ks += 2) {
    float wv0[8], wv1[8];
#pragma unroll
    for (int jj = 0; jj < 8; jj++) wv0[jj] = Wp[(size_t)(ks * 16 + jj) * N];
#pragma unroll
    for (int jj = 0; jj < 8; jj++) wv1[jj] = Wp[(size_t)(ks * 16 + 16 + jj) * N];
    uint4 b0, b1;
    b0.x = pk2bf(wv0[0], wv0[1]); b0.y = pk2bf(wv0[2], wv0[3]);
    b0.z = pk2bf(wv0[4], wv0[5]); b0.w = pk2bf(wv0[6], wv0[7]);
    b1.x = pk2bf(wv1[0], wv1[1]); b1.y = pk2bf(wv1[2], wv1[3]);
    b1.z = pk2bf(wv1[4], wv1[5]); b1.w = pk2bf(wv1[6], wv1[7]);
    bf16x8 af0 = *(const bf16x8*)((const char*)As + ((abase + ks * 32) ^ aswz));
    bf16x8 af1 = *(const bf16x8*)((const char*)As + ((abase + ks * 32 + 32) ^ aswz));
    acc0 = __builtin_amdgcn_mfma_f32_32x32x16_bf16(af0, *(const bf16x8*)&b0, acc0, 0, 0, 0);
    acc1 = __builtin_amdgcn_mfma_f32_32x32x16_bf16(af1, *(const bf16x8*)&b1, acc1, 0, 0, 0);
  }
  if (ks < nks) {
    float wv0[8];
#pragma unroll
    for (int jj = 0; jj < 8; jj++) wv0[jj] = Wp[(size_t)(ks * 16 + jj) * N];
    uint4 b0;
    b0.x = pk2bf(wv0[0], wv0[1]); b0.y = pk2bf(wv0[2], wv0[3]);
    b0.z = pk2bf(wv0[4], wv0[5]); b0.w = pk2bf(wv0[6], wv0[7]);
    bf16x8 af0 = *(const bf16x8*)((const char*)As + ((abase + ks * 32) ^ aswz));
    acc0 = __builtin_amdgcn_mfma_f32_32x32x16_bf16(af0, *(const bf16x8*)&b0, acc0, 0, 0, 0);
  }
  float* Pr = P + (size_t)blockIdx.y * 32 * N + col;
#pragma unroll
  for (int r = 0; r < 16; r++) {
    int row = (r & 3) + 8 * (r >> 2) + 4 * lh;
    Pr[(size_t)row * N] = acc0[r] + acc1[r];
  }
}

// ================= reduce partials + bias + act (+ bf16 copy) (+ fused final combine) =================
__global__ __launch_bounds__(256) void reduce_kernel(const float* __restrict__ P,
                                                     const float* __restrict__ bias,
                                                     float* __restrict__ dst,
                                                     unsigned short* __restrict__ dstbf,
                                                     int lnN, int KS, int act, int wbf,
                                                     const float* __restrict__ S,
                                                     const float* __restrict__ Ip,
                                                     float* __restrict__ out0, int comb) {
  const int idx = blockIdx.x * 256 + threadIdx.x;
  const int N = 1 << lnN;
  const int m = idx >> lnN, n = idx & (N - 1);
  float s = 0.f;
#pragma unroll 8
  for (int p = 0; p < KS; p++) s += P[((size_t)(p * 32 + m) << lnN) + n];
  s += bias[n];
  if (act == 1) s = fmaxf(s, 0.f);
  else if (act == 2) s = tanhf(s);
  dst[idx] = s;
  if (wbf) dstbf[idx] = f2bf(s);
  if (comb) out0[idx] = S[idx] + 0.1f * (Ip[idx] + s);
}

// ================= interaction core v6 (R9-proven): V via LDS, persistent-B =================
__global__ __launch_bounds__(512, 2) void inter6_kernel(const f16* __restrict__ Uh,
                                                        const f16* __restrict__ Vh,
                                                        const f16* __restrict__ W2h,
                                                        const float* __restrict__ bi2,
                                                        float* __restrict__ Hsum) {
  __shared__ __align__(16) f16 Bt[128 * 512]; // 128KB
  __shared__ __align__(16) f16 Vc[64 * 128];  // 16KB
  const int t = threadIdx.x;
  const int nq = blockIdx.x;

#pragma unroll
  for (int i = 0; i < 16; i++) {
    int idx = i * 512 + t;
    int n = idx >> 6, ch = idx & 63;
    f16x8 w8 = *(const f16x8*)&W2h[(size_t)(nq * 128 + n) * 512 + ch * 8];
    int off = (n * 1024 + ch * 16) ^ ((n & 15) << 4);
    *(f16x8*)((char*)Bt + off) = w8;
  }

  const int w = t >> 6, lane = t & 63;
  const int ii = w & 1, tg = w >> 1;
  const int lrow = lane & 31, lh = lane >> 5;
  const char* Btc = (const char*)Bt;
  const char* Vcc = (const char*)Vc;
  char* Vcw = (char*)Vc;

  int bofs[4], bswz[4];
#pragma unroll
  for (int nf = 0; nf < 4; nf++) {
    int nr = nf * 32 + lrow;
    bofs[nf] = nr * 1024 + lh * 16;
    bswz[nf] = (nr & 15) << 4;
  }
  const int vofs0 = lrow * 256;
  const int vswz0 = (lrow & 15) << 4;
  const int vofs1 = (lrow + 32) * 256;
  const int vswz1 = vswz0;

  const int b = blockIdx.y >> 1;

  for (int s = 0; s < 4; s++) {
    const int tid = blockIdx.y * 16 + tg * 4 + s;
    const int it = tid & 31;
    const f16* Ub = Uh + (size_t)(b * 64 + it * 2 + ii) * 512 + lh * 8;

    f32x16 acc[2][4];
#pragma unroll
    for (int mf = 0; mf < 2; mf++)
#pragma unroll
      for (int nf = 0; nf < 4; nf++)
#pragma unroll
        for (int r = 0; r < 16; r++) acc[mf][nf][r] = 0.f;

    for (int ch = 0; ch < 4; ch++) {
      const int kc = ch * 128;
      __syncthreads();
#pragma unroll
      for (int i = 0; i < 2; i++) {
        int idx = i * 512 + t;
        int row = idx >> 4, c8 = idx & 15;
        f16x8 w8 = *(const f16x8*)&Vh[(size_t)(b * 64 + row) * 512 + kc + c8 * 8];
        *(f16x8*)(Vcw + ((row * 256 + c8 * 16) ^ ((row & 15) << 4))) = w8;
      }
      __syncthreads();
#pragma unroll
      for (int k16 = 0; k16 < 8; k16++) {
        const int kb2 = k16 * 32 + lh * 16;
        f16x8 v0 = *(const f16x8*)(Vcc + ((vofs0 + kb2) ^ vswz0));
        f16x8 v1 = *(const f16x8*)(Vcc + ((vofs1 + kb2) ^ vswz1));
        f16x8 u0 = *(const f16x8*)(Ub + kc + k16 * 16);
        f16x8 a0 = relu8(v0 + u0);
        f16x8 a1 = relu8(v1 + u0);
#pragma unroll
        for (int nf = 0; nf < 4; nf++) {
          f16x8 bfr = *(const f16x8*)(Btc + ((bofs[nf] + (kc + k16 * 16) * 2) ^ bswz[nf]));
          acc[0][nf] = __builtin_amdgcn_mfma_f32_32x32x16_f16(a0, bfr, acc[0][nf], 0, 0, 0);
          acc[1][nf] = __builtin_amdgcn_mfma_f32_32x32x16_f16(a1, bfr, acc[1][nf], 0, 0, 0);
        }
      }
    }

    const int iglob = it * 2 + ii;
    const int mf_d = iglob >> 5;
    const int rd = iglob & 31;
    const int lh_d = (rd >> 2) & 1;
    const int r_d = (rd & 3) + 4 * (rd >> 3);
#pragma unroll
    for (int nf = 0; nf < 4; nf++) {
      const int col = nq * 128 + nf * 32 + lrow;
      const float b2 = bi2[col];
      float ssum = 0.f;
#pragma unroll
      for (int mf = 0; mf < 2; mf++)
#pragma unroll
        for (int r = 0; r < 16; r++) {
          float x = fmaxf(acc[mf][nf][r] + b2, 0.f);
          if (mf == mf_d && r == r_d && lh == lh_d) x = 0.f;
          ssum += x;
        }
      ssum += __shfl_xor(ssum, 32);
      if (lh == 0) Hsum[(size_t)(b * 64 + iglob) * 512 + col] = ssum;
    }
  }
}

// ---------------- interactions = (Hsum/63) @ Wi3 + bi3, 256 blocks ----------------
__global__ __launch_bounds__(256) void k3_kernel(const float* __restrict__ Hsum,
                                                 const float* __restrict__ Wi3,
                                                 const float* __restrict__ bi3,
                                                 float* __restrict__ inter) {
  __shared__ float st[512][10];
  const int t = threadIdx.x;
  const int row0 = blockIdx.x * 8;
  for (int idx = t; idx < 4096; idx += 256) {
    int r = idx >> 9, k = idx & 511;
    st[k][r] = Hsum[(row0 + r) * 512 + k] * (1.0f / 63.0f);
  }
  __syncthreads();
  const int c = t & 63;
  const int rg = t >> 6;
  float a0[2] = {0.f, 0.f}, a1[2] = {0.f, 0.f};
#pragma unroll 4
  for (int k = 0; k < 512; k++) {
    float w0 = Wi3[k * 128 + c];
    float w1 = Wi3[k * 128 + 64 + c];
    float2 h = *(const float2*)&st[k][rg * 2];
    a0[0] += h.x * w0; a0[1] += h.y * w0;
    a1[0] += h.x * w1; a1[1] += h.y * w1;
  }
  float b0 = bi3[c], b1 = bi3[64 + c];
#pragma unroll
  for (int r = 0; r < 2; r++) {
    inter[(row0 + rg * 2 + r) * 128 + c]      = a0[r] + b0;
    inter[(row0 + rg * 2 + r) * 128 + 64 + c] = a1[r] + b1;
  }
}

extern "C" void kernel_launch(void* const* d_in, const int* in_sizes, int n_in,
                              void* d_out, int out_size, void* d_ws, size_t ws_size,
                              hipStream_t stream) {
  const float* states = (const float*)d_in[0];
  const float* Wq  = (const float*)d_in[2];
  const float* bq  = (const float*)d_in[3];
  const float* Wi1 = (const float*)d_in[4];
  const float* bi1 = (const float*)d_in[5];
  const float* Wi2 = (const float*)d_in[6];
  const float* bi2 = (const float*)d_in[7];
  const float* Wi3 = (const float*)d_in[8];
  const float* bi3 = (const float*)d_in[9];
  const float* Wc1 = (const float*)d_in[10];
  const float* bc1 = (const float*)d_in[11];
  const float* Wc2 = (const float*)d_in[12];
  const float* bc2 = (const float*)d_in[13];
  const float* Wc3 = (const float*)d_in[14];
  const float* bc3 = (const float*)d_in[15];

  float* out   = (float*)d_out;
  float* out0  = out;            // coordinated_states (B,A,D)
  float* qf    = out + 262144;   // quantum_features (B,F)
  float* inter = out + 524288;   // interactions (B,A,D)
  float* coord = out + 786432;   // coordination (B,A,D)

  char* ws = (char*)d_ws;
  float*          P    = (float*)(ws);                                   // 16MB partials
  f16*            Uh   = (f16*)(ws + ((size_t)16 << 20));                // 2MB
  f16*            Vh   = (f16*)(ws + ((size_t)19 << 20));                // 2MB
  f16*            W2h  = (f16*)(ws + ((size_t)22 << 20));                // 0.5MB
  float*          Hsum = (float*)(ws + ((size_t)23 << 20));              // 4MB
  unsigned short* Sbf  = (unsigned short*)(ws + ((size_t)27 << 20));     // 0.5MB
  unsigned short* qfbf = (unsigned short*)(ws + ((size_t)28 << 20));     // 0.5MB
  float*          c1   = (float*)(ws + ((size_t)29 << 20));              // 64KB
  float*          c2   = (float*)(ws + ((size_t)29 << 20) + (1 << 16));  // 64KB
  unsigned short* c1bf = (unsigned short*)(ws + ((size_t)29 << 20) + (2 << 16)); // 32KB
  unsigned short* c2bf = (unsigned short*)(ws + ((size_t)29 << 20) + (3 << 16)); // 32KB

  // fused prep: tobf + w2h + uvh  (3 launches -> 1)
  prep_kernel<<<768, 256, 0, stream>>>(states, Wi2, Wi1, bi1, Sbf, W2h, Uh, Vh);

  // quantum features: qf = tanh(states @ Wq + bq)   K=8192 N=8192, KS=16, L=512
  gemmw<<<dim3(64, 16), 256, 0, stream>>>(Sbf, Wq, P, 8192, 8192, 512, 7);
  reduce_kernel<<<1024, 256, 0, stream>>>(P, bq, qf, qfbf, 13, 16, 2, 1,
                                          nullptr, nullptr, nullptr, 0);

  // interactions
  inter6_kernel<<<dim3(4, 64), 512, 0, stream>>>(Uh, Vh, W2h, bi2, Hsum);
  k3_kernel<<<256, 256, 0, stream>>>(Hsum, Wi3, bi3, inter);

  // coordination chain
  gemmw<<<dim3(4, 64), 256, 0, stream>>>(qfbf, Wc1, P, 8192, 512, 128, 5);
  reduce_kernel<<<64, 256, 0, stream>>>(P, bc1, c1, c1bf, 9, 64, 1, 1,
                                        nullptr, nullptr, nullptr, 0);
  gemmw<<<dim3(4, 32), 256, 0, stream>>>(c1bf, Wc2, P, 512, 512, 16, 2);
  reduce_kernel<<<64, 256, 0, stream>>>(P, bc2, c2, c2bf, 9, 32, 1, 1,
                                        nullptr, nullptr, nullptr, 0);

  // coord = c2 @ Wc3 + bc3 + fused final combine (saves 1 launch + a 3MB pass)
  gemmw<<<dim3(64, 8), 256, 0, stream>>>(c2bf, Wc3, P, 512, 8192, 64, 4);
  reduce_kernel<<<1024, 256, 0, stream>>>(P, bc3, coord, nullptr, 13, 8, 0, 0,
                                          states, inter, out0, 1);
}

// Round 20
// 218.989 us; speedup vs baseline: 1.1517x; 1.0018x over previous
//
#include <hip/hip_runtime.h>

typedef __attribute__((ext_vector_type(8))) short bf16x8;
typedef __attribute__((ext_vector_type(16))) float f32x16;
typedef _Float16 f16;
typedef __attribute__((ext_vector_type(8))) _Float16 f16x8;

static __device__ __forceinline__ unsigned short f2bf(float x) {
  unsigned int u = __float_as_uint(x);
  return (unsigned short)((u + 0x7FFFu + ((u >> 16) & 1u)) >> 16);
}
static __device__ __forceinline__ unsigned int pk2bf(float lo, float hi) {
  return ((unsigned int)f2bf(hi) << 16) | f2bf(lo);
}
static __device__ __forceinline__ f16x8 relu8(f16x8 x) {
  f16x8 z = {0, 0, 0, 0, 0, 0, 0, 0};
  return __builtin_elementwise_max(x, z);
}

// ================= fused prep: tobf (blocks 0..255), w2h (256..511), uvh (512..767) =================
__global__ __launch_bounds__(256) void prep_kernel(const float* __restrict__ states,
                                                   const float* __restrict__ Wi2,
                                                   const float* __restrict__ Wi1,
                                                   const float* __restrict__ bi1,
                                                   unsigned short* __restrict__ Sbf,
                                                   f16* __restrict__ W2h,
                                                   f16* __restrict__ Uh, f16* __restrict__ Vh) {
  __shared__ float lds_f[1536];
  const int t = threadIdx.x;
  const int bid = blockIdx.x;
  if (bid < 256) {
    const int idx = bid * 256 + t;
    float4 v = ((const float4*)states)[idx];
    ushort4 o;
    o.x = f2bf(v.x); o.y = f2bf(v.y); o.z = f2bf(v.z); o.w = f2bf(v.w);
    ((ushort4*)Sbf)[idx] = o;
  } else if (bid < 512) {
    const int b = bid - 256;
    const int bk = b & 15, bn = b >> 4;
    float (*tile)[33] = (float(*)[33])lds_f;
    const int r = t >> 5, c = t & 31;
#pragma unroll
    for (int p = 0; p < 4; p++) {
      int rr = p * 8 + r;
      tile[rr][c] = Wi2[(bk * 32 + rr) * 512 + bn * 32 + c];
    }
    __syncthreads();
#pragma unroll
    for (int p = 0; p < 4; p++) {
      int rr = p * 8 + r;
      W2h[(bn * 32 + rr) * 512 + bk * 32 + c] = (f16)tile[c][rr];
    }
  } else {
    const int row0 = (bid - 512) * 8;
    float (*st)[12] = (float(*)[12])lds_f;
    for (int idx = t; idx < 1024; idx += 256) {
      int r = idx >> 7, k = idx & 127;
      st[k][r] = states[(row0 + r) * 128 + k];
    }
    __syncthreads();
    float au0[8], au1[8], av0[8], av1[8];
#pragma unroll
    for (int r = 0; r < 8; r++) { au0[r] = 0.f; au1[r] = 0.f; av0[r] = 0.f; av1[r] = 0.f; }
#pragma unroll 4
    for (int k = 0; k < 128; k++) {
      float wt0 = Wi1[k * 512 + t];
      float wt1 = Wi1[k * 512 + 256 + t];
      float wb0 = Wi1[(k + 128) * 512 + t];
      float wb1 = Wi1[(k + 128) * 512 + 256 + t];
      float4 sA = *(const float4*)&st[k][0];
      float4 sB = *(const float4*)&st[k][4];
      float s8[8] = {sA.x, sA.y, sA.z, sA.w, sB.x, sB.y, sB.z, sB.w};
#pragma unroll
      for (int r = 0; r < 8; r++) {
        au0[r] += s8[r] * wt0;
        au1[r] += s8[r] * wt1;
        av0[r] += s8[r] * wb0;
        av1[r] += s8[r] * wb1;
      }
    }
    const float b0 = bi1[t], b1 = bi1[256 + t];
#pragma unroll
    for (int r = 0; r < 8; r++) {
      Uh[(row0 + r) * 512 + t]       = (f16)(au0[r] + b0);
      Uh[(row0 + r) * 512 + 256 + t] = (f16)(au1[r] + b1);
      Vh[(row0 + r) * 512 + t]       = (f16)av0[r];
      Vh[(row0 + r) * 512 + 256 + t] = (f16)av1[r];
    }
  }
}

// ---------------- MFMA M=32 weight-streaming GEMM (2-bank body, 5 blocks/CU) ----------------
// VGPR: allocator freely chose 48 at (256,4); (256,5) caps at 51 -> no spill, +25% occupancy.
__global__ __launch_bounds__(256, 5) void gemmw(const unsigned short* __restrict__ Abf,
                                                const float* __restrict__ W,
                                                float* __restrict__ P,
                                                int K, int N, int L, int l4sh) {
  __shared__ __align__(16) unsigned short As[32 * 512];
  const int t = threadIdx.x;
  const int k0 = blockIdx.y * L;
  const int L4 = L >> 2;
  const int swzm = 2 * L - 1;
  for (int idx = t; idx < (L << 3); idx += 256) {
    int row = idx >> l4sh, k4 = idx & (L4 - 1);
    ushort4 a4 = *(const ushort4*)&Abf[(size_t)row * K + k0 + k4 * 4];
    int off = (row * 2 * L + k4 * 8) ^ (((row & 7) << 4) & swzm);
    *(ushort4*)((char*)As + off) = a4;
  }
  __syncthreads();
  const int lane = t & 63, w = t >> 6;
  const int lrow = lane & 31, lh = lane >> 5;
  const int col = blockIdx.x * 128 + w * 32 + lrow;
  f32x16 acc0, acc1;
#pragma unroll
  for (int r = 0; r < 16; r++) { acc0[r] = 0.f; acc1[r] = 0.f; }
  const float* Wp = W + (size_t)(k0 + lh * 8) * N + col;
  const int aswz = ((lrow & 7) << 4) & swzm;
  const int abase = lrow * 2 * L + lh * 16;
  const int nks = L >> 4;
  int ks = 0;
  for (; ks + 1 < nks; ks += 2) {
    float wv0[8], wv1[8];
#pragma unroll
    for (int jj = 0; jj < 8; jj++) wv0[jj] = Wp[(size_t)(ks * 16 + jj) * N];
#pragma unroll
    for (int jj = 0; jj < 8; jj++) wv1[jj] = Wp[(size_t)(ks * 16 + 16 + jj) * N];
    uint4 b0, b1;
    b0.x = pk2bf(wv0[0], wv0[1]); b0.y = pk2bf(wv0[2], wv0[3]);
    b0.z = pk2bf(wv0[4], wv0[5]); b0.w = pk2bf(wv0[6], wv0[7]);
    b1.x = pk2bf(wv1[0], wv1[1]); b1.y = pk2bf(wv1[2], wv1[3]);
    b1.z = pk2bf(wv1[4], wv1[5]); b1.w = pk2bf(wv1[6], wv1[7]);
    bf16x8 af0 = *(const bf16x8*)((const char*)As + ((abase + ks * 32) ^ aswz));
    bf16x8 af1 = *(const bf16x8*)((const char*)As + ((abase + ks * 32 + 32) ^ aswz));
    acc0 = __builtin_amdgcn_mfma_f32_32x32x16_bf16(af0, *(const bf16x8*)&b0, acc0, 0, 0, 0);
    acc1 = __builtin_amdgcn_mfma_f32_32x32x16_bf16(af1, *(const bf16x8*)&b1, acc1, 0, 0, 0);
  }
  if (ks < nks) {
    float wv0[8];
#pragma unroll
    for (int jj = 0; jj < 8; jj++) wv0[jj] = Wp[(size_t)(ks * 16 + jj) * N];
    uint4 b0;
    b0.x = pk2bf(wv0[0], wv0[1]); b0.y = pk2bf(wv0[2], wv0[3]);
    b0.z = pk2bf(wv0[4], wv0[5]); b0.w = pk2bf(wv0[6], wv0[7]);
    bf16x8 af0 = *(const bf16x8*)((const char*)As + ((abase + ks * 32) ^ aswz));
    acc0 = __builtin_amdgcn_mfma_f32_32x32x16_bf16(af0, *(const bf16x8*)&b0, acc0, 0, 0, 0);
  }
  float* Pr = P + (size_t)blockIdx.y * 32 * N + col;
#pragma unroll
  for (int r = 0; r < 16; r++) {
    int row = (r & 3) + 8 * (r >> 2) + 4 * lh;
    Pr[(size_t)row * N] = acc0[r] + acc1[r];
  }
}

// ================= reduce partials + bias + act (+ bf16 copy) (+ fused final combine) =================
__global__ __launch_bounds__(256) void reduce_kernel(const float* __restrict__ P,
                                                     const float* __restrict__ bias,
                                                     float* __restrict__ dst,
                                                     unsigned short* __restrict__ dstbf,
                                                     int lnN, int KS, int act, int wbf,
                                                     const float* __restrict__ S,
                                                     const float* __restrict__ Ip,
                                                     float* __restrict__ out0, int comb) {
  const int idx = blockIdx.x * 256 + threadIdx.x;
  const int N = 1 << lnN;
  const int m = idx >> lnN, n = idx & (N - 1);
  float s = 0.f;
#pragma unroll 8
  for (int p = 0; p < KS; p++) s += P[((size_t)(p * 32 + m) << lnN) + n];
  s += bias[n];
  if (act == 1) s = fmaxf(s, 0.f);
  else if (act == 2) s = tanhf(s);
  dst[idx] = s;
  if (wbf) dstbf[idx] = f2bf(s);
  if (comb) out0[idx] = S[idx] + 0.1f * (Ip[idx] + s);
}

// ================= interaction core v6 (R9-proven): V via LDS, persistent-B =================
__global__ __launch_bounds__(512, 2) void inter6_kernel(const f16* __restrict__ Uh,
                                                        const f16* __restrict__ Vh,
                                                        const f16* __restrict__ W2h,
                                                        const float* __restrict__ bi2,
                                                        float* __restrict__ Hsum) {
  __shared__ __align__(16) f16 Bt[128 * 512]; // 128KB
  __shared__ __align__(16) f16 Vc[64 * 128];  // 16KB
  const int t = threadIdx.x;
  const int nq = blockIdx.x;

#pragma unroll
  for (int i = 0; i < 16; i++) {
    int idx = i * 512 + t;
    int n = idx >> 6, ch = idx & 63;
    f16x8 w8 = *(const f16x8*)&W2h[(size_t)(nq * 128 + n) * 512 + ch * 8];
    int off = (n * 1024 + ch * 16) ^ ((n & 15) << 4);
    *(f16x8*)((char*)Bt + off) = w8;
  }

  const int w = t >> 6, lane = t & 63;
  const int ii = w & 1, tg = w >> 1;
  const int lrow = lane & 31, lh = lane >> 5;
  const char* Btc = (const char*)Bt;
  const char* Vcc = (const char*)Vc;
  char* Vcw = (char*)Vc;

  int bofs[4], bswz[4];
#pragma unroll
  for (int nf = 0; nf < 4; nf++) {
    int nr = nf * 32 + lrow;
    bofs[nf] = nr * 1024 + lh * 16;
    bswz[nf] = (nr & 15) << 4;
  }
  const int vofs0 = lrow * 256;
  const int vswz0 = (lrow & 15) << 4;
  const int vofs1 = (lrow + 32) * 256;
  const int vswz1 = vswz0;

  const int b = blockIdx.y >> 1;

  for (int s = 0; s < 4; s++) {
    const int tid = blockIdx.y * 16 + tg * 4 + s;
    const int it = tid & 31;
    const f16* Ub = Uh + (size_t)(b * 64 + it * 2 + ii) * 512 + lh * 8;

    f32x16 acc[2][4];
#pragma unroll
    for (int mf = 0; mf < 2; mf++)
#pragma unroll
      for (int nf = 0; nf < 4; nf++)
#pragma unroll
        for (int r = 0; r < 16; r++) acc[mf][nf][r] = 0.f;

    for (int ch = 0; ch < 4; ch++) {
      const int kc = ch * 128;
      __syncthreads();
#pragma unroll
      for (int i = 0; i < 2; i++) {
        int idx = i * 512 + t;
        int row = idx >> 4, c8 = idx & 15;
        f16x8 w8 = *(const f16x8*)&Vh[(size_t)(b * 64 + row) * 512 + kc + c8 * 8];
        *(f16x8*)(Vcw + ((row * 256 + c8 * 16) ^ ((row & 15) << 4))) = w8;
      }
      __syncthreads();
#pragma unroll
      for (int k16 = 0; k16 < 8; k16++) {
        const int kb2 = k16 * 32 + lh * 16;
        f16x8 v0 = *(const f16x8*)(Vcc + ((vofs0 + kb2) ^ vswz0));
        f16x8 v1 = *(const f16x8*)(Vcc + ((vofs1 + kb2) ^ vswz1));
        f16x8 u0 = *(const f16x8*)(Ub + kc + k16 * 16);
        f16x8 a0 = relu8(v0 + u0);
        f16x8 a1 = relu8(v1 + u0);
#pragma unroll
        for (int nf = 0; nf < 4; nf++) {
          f16x8 bfr = *(const f16x8*)(Btc + ((bofs[nf] + (kc + k16 * 16) * 2) ^ bswz[nf]));
          acc[0][nf] = __builtin_amdgcn_mfma_f32_32x32x16_f16(a0, bfr, acc[0][nf], 0, 0, 0);
          acc[1][nf] = __builtin_amdgcn_mfma_f32_32x32x16_f16(a1, bfr, acc[1][nf], 0, 0, 0);
        }
      }
    }

    const int iglob = it * 2 + ii;
    const int mf_d = iglob >> 5;
    const int rd = iglob & 31;
    const int lh_d = (rd >> 2) & 1;
    const int r_d = (rd & 3) + 4 * (rd >> 3);
#pragma unroll
    for (int nf = 0; nf < 4; nf++) {
      const int col = nq * 128 + nf * 32 + lrow;
      const float b2 = bi2[col];
      float ssum = 0.f;
#pragma unroll
      for (int mf = 0; mf < 2; mf++)
#pragma unroll
        for (int r = 0; r < 16; r++) {
          float x = fmaxf(acc[mf][nf][r] + b2, 0.f);
          if (mf == mf_d && r == r_d && lh == lh_d) x = 0.f;
          ssum += x;
        }
      ssum += __shfl_xor(ssum, 32);
      if (lh == 0) Hsum[(size_t)(b * 64 + iglob) * 512 + col] = ssum;
    }
  }
}

// ---------------- interactions = (Hsum/63) @ Wi3 + bi3, 256 blocks ----------------
__global__ __launch_bounds__(256) void k3_kernel(const float* __restrict__ Hsum,
                                                 const float* __restrict__ Wi3,
                                                 const float* __restrict__ bi3,
                                                 float* __restrict__ inter) {
  __shared__ float st[512][10];
  const int t = threadIdx.x;
  const int row0 = blockIdx.x * 8;
  for (int idx = t; idx < 4096; idx += 256) {
    int r = idx >> 9, k = idx & 511;
    st[k][r] = Hsum[(row0 + r) * 512 + k] * (1.0f / 63.0f);
  }
  __syncthreads();
  const int c = t & 63;
  const int rg = t >> 6;
  float a0[2] = {0.f, 0.f}, a1[2] = {0.f, 0.f};
#pragma unroll 4
  for (int k = 0; k < 512; k++) {
    float w0 = Wi3[k * 128 + c];
    float w1 = Wi3[k * 128 + 64 + c];
    float2 h = *(const float2*)&st[k][rg * 2];
    a0[0] += h.x * w0; a0[1] += h.y * w0;
    a1[0] += h.x * w1; a1[1] += h.y * w1;
  }
  float b0 = bi3[c], b1 = bi3[64 + c];
#pragma unroll
  for (int r = 0; r < 2; r++) {
    inter[(row0 + rg * 2 + r) * 128 + c]      = a0[r] + b0;
    inter[(row0 + rg * 2 + r) * 128 + 64 + c] = a1[r] + b1;
  }
}

extern "C" void kernel_launch(void* const* d_in, const int* in_sizes, int n_in,
                              void* d_out, int out_size, void* d_ws, size_t ws_size,
                              hipStream_t stream) {
  const float* states = (const float*)d_in[0];
  const float* Wq  = (const float*)d_in[2];
  const float* bq  = (const float*)d_in[3];
  const float* Wi1 = (const float*)d_in[4];
  const float* bi1 = (const float*)d_in[5];
  const float* Wi2 = (const float*)d_in[6];
  const float* bi2 = (const float*)d_in[7];
  const float* Wi3 = (const float*)d_in[8];
  const float* bi3 = (const float*)d_in[9];
  const float* Wc1 = (const float*)d_in[10];
  const float* bc1 = (const float*)d_in[11];
  const float* Wc2 = (const float*)d_in[12];
  const float* bc2 = (const float*)d_in[13];
  const float* Wc3 = (const float*)d_in[14];
  const float* bc3 = (const float*)d_in[15];

  float* out   = (float*)d_out;
  float* out0  = out;            // coordinated_states (B,A,D)
  float* qf    = out + 262144;   // quantum_features (B,F)
  float* inter = out + 524288;   // interactions (B,A,D)
  float* coord = out + 786432;   // coordination (B,A,D)

  char* ws = (char*)d_ws;
  float*          P    = (float*)(ws);                                   // 16MB partials
  f16*            Uh   = (f16*)(ws + ((size_t)16 << 20));                // 2MB
  f16*            Vh   = (f16*)(ws + ((size_t)19 << 20));                // 2MB
  f16*            W2h  = (f16*)(ws + ((size_t)22 << 20));                // 0.5MB
  float*          Hsum = (float*)(ws + ((size_t)23 << 20));              // 4MB
  unsigned short* Sbf  = (unsigned short*)(ws + ((size_t)27 << 20));     // 0.5MB
  unsigned short* qfbf = (unsigned short*)(ws + ((size_t)28 << 20));     // 0.5MB
  float*          c1   = (float*)(ws + ((size_t)29 << 20));              // 64KB
  float*          c2   = (float*)(ws + ((size_t)29 << 20) + (1 << 16));  // 64KB
  unsigned short* c1bf = (unsigned short*)(ws + ((size_t)29 << 20) + (2 << 16)); // 32KB
  unsigned short* c2bf = (unsigned short*)(ws + ((size_t)29 << 20) + (3 << 16)); // 32KB

  // fused prep: tobf + w2h + uvh  (3 launches -> 1)
  prep_kernel<<<768, 256, 0, stream>>>(states, Wi2, Wi1, bi1, Sbf, W2h, Uh, Vh);

  // quantum features: qf = tanh(states @ Wq + bq)   K=8192 N=8192, KS=16, L=512
  gemmw<<<dim3(64, 16), 256, 0, stream>>>(Sbf, Wq, P, 8192, 8192, 512, 7);
  reduce_kernel<<<1024, 256, 0, stream>>>(P, bq, qf, qfbf, 13, 16, 2, 1,
                                          nullptr, nullptr, nullptr, 0);

  // interactions
  inter6_kernel<<<dim3(4, 64), 512, 0, stream>>>(Uh, Vh, W2h, bi2, Hsum);
  k3_kernel<<<256, 256, 0, stream>>>(Hsum, Wi3, bi3, inter);

  // coordination chain
  gemmw<<<dim3(4, 64), 256, 0, stream>>>(qfbf, Wc1, P, 8192, 512, 128, 5);
  reduce_kernel<<<64, 256, 0, stream>>>(P, bc1, c1, c1bf, 9, 64, 1, 1,
                                        nullptr, nullptr, nullptr, 0);
  gemmw<<<dim3(4, 32), 256, 0, stream>>>(c1bf, Wc2, P, 512, 512, 16, 2);
  reduce_kernel<<<64, 256, 0, stream>>>(P, bc2, c2, c2bf, 9, 32, 1, 1,
                                        nullptr, nullptr, nullptr, 0);

  // coord = c2 @ Wc3 + bc3 + fused final combine
  gemmw<<<dim3(64, 8), 256, 0, stream>>>(c2bf, Wc3, P, 512, 8192, 64, 4);
  reduce_kernel<<<1024, 256, 0, stream>>>(P, bc3, coord, nullptr, 13, 8, 0, 0,
                                          states, inter, out0, 1);
}

// Round 21
// 217.163 us; speedup vs baseline: 1.1614x; 1.0084x over previous
//
#include <hip/hip_runtime.h>

typedef __attribute__((ext_vector_type(8))) short bf16x8;
typedef __attribute__((ext_vector_type(16))) float f32x16;
typedef _Float16 f16;
typedef __attribute__((ext_vector_type(8))) _Float16 f16x8;

static __device__ __forceinline__ unsigned short f2bf(float x) {
  unsigned int u = __float_as_uint(x);
  return (unsigned short)((u + 0x7FFFu + ((u >> 16) & 1u)) >> 16);
}
static __device__ __forceinline__ unsigned int pk2bf(float lo, float hi) {
  return ((unsigned int)f2bf(hi) << 16) | f2bf(lo);
}
static __device__ __forceinline__ f16x8 relu8(f16x8 x) {
  f16x8 z = {0, 0, 0, 0, 0, 0, 0, 0};
  return __builtin_elementwise_max(x, z);
}

// ================= fused prep: tobf (blocks 0..255), w2h (256..511), uvh (512..767) =================
__global__ __launch_bounds__(256) void prep_kernel(const float* __restrict__ states,
                                                   const float* __restrict__ Wi2,
                                                   const float* __restrict__ Wi1,
                                                   const float* __restrict__ bi1,
                                                   unsigned short* __restrict__ Sbf,
                                                   f16* __restrict__ W2h,
                                                   f16* __restrict__ Uh, f16* __restrict__ Vh) {
  __shared__ float lds_f[1536];
  const int t = threadIdx.x;
  const int bid = blockIdx.x;
  if (bid < 256) {
    const int idx = bid * 256 + t;
    float4 v = ((const float4*)states)[idx];
    ushort4 o;
    o.x = f2bf(v.x); o.y = f2bf(v.y); o.z = f2bf(v.z); o.w = f2bf(v.w);
    ((ushort4*)Sbf)[idx] = o;
  } else if (bid < 512) {
    const int b = bid - 256;
    const int bk = b & 15, bn = b >> 4;
    float (*tile)[33] = (float(*)[33])lds_f;
    const int r = t >> 5, c = t & 31;
#pragma unroll
    for (int p = 0; p < 4; p++) {
      int rr = p * 8 + r;
      tile[rr][c] = Wi2[(bk * 32 + rr) * 512 + bn * 32 + c];
    }
    __syncthreads();
#pragma unroll
    for (int p = 0; p < 4; p++) {
      int rr = p * 8 + r;
      W2h[(bn * 32 + rr) * 512 + bk * 32 + c] = (f16)tile[c][rr];
    }
  } else {
    const int row0 = (bid - 512) * 8;
    float (*st)[12] = (float(*)[12])lds_f;
    for (int idx = t; idx < 1024; idx += 256) {
      int r = idx >> 7, k = idx & 127;
      st[k][r] = states[(row0 + r) * 128 + k];
    }
    __syncthreads();
    float au0[8], au1[8], av0[8], av1[8];
#pragma unroll
    for (int r = 0; r < 8; r++) { au0[r] = 0.f; au1[r] = 0.f; av0[r] = 0.f; av1[r] = 0.f; }
#pragma unroll 4
    for (int k = 0; k < 128; k++) {
      float wt0 = Wi1[k * 512 + t];
      float wt1 = Wi1[k * 512 + 256 + t];
      float wb0 = Wi1[(k + 128) * 512 + t];
      float wb1 = Wi1[(k + 128) * 512 + 256 + t];
      float4 sA = *(const float4*)&st[k][0];
      float4 sB = *(const float4*)&st[k][4];
      float s8[8] = {sA.x, sA.y, sA.z, sA.w, sB.x, sB.y, sB.z, sB.w};
#pragma unroll
      for (int r = 0; r < 8; r++) {
        au0[r] += s8[r] * wt0;
        au1[r] += s8[r] * wt1;
        av0[r] += s8[r] * wb0;
        av1[r] += s8[r] * wb1;
      }
    }
    const float b0 = bi1[t], b1 = bi1[256 + t];
#pragma unroll
    for (int r = 0; r < 8; r++) {
      Uh[(row0 + r) * 512 + t]       = (f16)(au0[r] + b0);
      Uh[(row0 + r) * 512 + 256 + t] = (f16)(au1[r] + b1);
      Vh[(row0 + r) * 512 + t]       = (f16)av0[r];
      Vh[(row0 + r) * 512 + 256 + t] = (f16)av1[r];
    }
  }
}

// ===== gemmw3: LDS-staged-B weight streaming for Wq (L=512, N%128==0) =====
// Block 256thr = 4 waves; tile 128 cols x 512 k. Per 16-k step: block-wide coalesced
// float4 row loads (32 thr = 512B burst, 8 rows in flight), f32->bf16, fragment-major
// Bs [lh][n][j] (b128 reads conflict-free; writes XOR-swizzled by (n>>3)&7). Double
// buffer, 1 barrier/step, loads issued before compute (T14 split).
__global__ __launch_bounds__(256, 4) void gemmw3(const unsigned short* __restrict__ Abf,
                                                 const float* __restrict__ W,
                                                 float* __restrict__ P,
                                                 int K, int N) {
  __shared__ __align__(16) unsigned short As[32 * 512]; // 32KB
  __shared__ __align__(16) char Bs[8192];               // 2 x 4KB fragment-major
  const int t = threadIdx.x;
  const int k0 = blockIdx.y * 512;
  // stage A: 32 rows x 512 k bf16, swizzled
  for (int idx = t; idx < 4096; idx += 256) {
    int row = idx >> 7, k4 = idx & 127;
    ushort4 a4 = *(const ushort4*)&Abf[(size_t)row * K + k0 + k4 * 4];
    int off = (row * 1024 + k4 * 8) ^ ((row & 7) << 4);
    *(ushort4*)((char*)As + off) = a4;
  }

  const int lane = t & 63, w = t >> 6;
  const int lrow = lane & 31, lh = lane >> 5;
  const int c0 = blockIdx.x * 128;
  const int srow = t >> 5;          // staging row 0..7 (x2 iters)
  const int sc4 = t & 31;           // staging float4 col
  const float* Wst = W + (size_t)k0 * N + c0 + sc4 * 4;

  // B-frag read address (n = wave col), XOR bits>=4 only
  const int nr = w * 32 + lrow;
  const int bread = lh * 2048 + ((nr * 16) ^ (((nr >> 3) & 7) << 4));
  const int abase = lrow * 1024 + lh * 16;
  const int aswz = (lrow & 7) << 4;

  f32x16 acc;
#pragma unroll
  for (int r = 0; r < 16; r++) acc[r] = 0.f;

  float4 r0, r1;
  // prologue: load step 0
  r0 = *(const float4*)&Wst[(size_t)(srow) * N];
  r1 = *(const float4*)&Wst[(size_t)(srow + 8) * N];
  __syncthreads();  // A-stage complete

  for (int ks = 0; ks < 32; ks++) {
    // write staged regs into Bs[ks&1]
    char* bb = Bs + (ks & 1) * 4096;
    {
      int lh0 = srow >> 3, j0 = srow & 7;          // r0: row = srow
      int lh1 = (srow + 8) >> 3, j1 = srow & 7;    // r1: row = srow+8
      float v0[4] = {r0.x, r0.y, r0.z, r0.w};
      float v1[4] = {r1.x, r1.y, r1.z, r1.w};
#pragma unroll
      for (int cc = 0; cc < 4; cc++) {
        int n = sc4 * 4 + cc;
        int sl = (n * 16) ^ (((n >> 3) & 7) << 4);
        *(unsigned short*)(bb + lh0 * 2048 + sl + j0 * 2) = f2bf(v0[cc]);
        *(unsigned short*)(bb + lh1 * 2048 + sl + j1 * 2) = f2bf(v1[cc]);
      }
    }
    __syncthreads();
    // issue loads for next step (fly under compute)
    if (ks < 31) {
      r0 = *(const float4*)&Wst[(size_t)((ks + 1) * 16 + srow) * N];
      r1 = *(const float4*)&Wst[(size_t)((ks + 1) * 16 + srow + 8) * N];
    }
    // compute step ks
    bf16x8 af = *(const bf16x8*)((const char*)As + ((abase + ks * 32) ^ aswz));
    bf16x8 bf = *(const bf16x8*)(Bs + (ks & 1) * 4096 + bread);
    acc = __builtin_amdgcn_mfma_f32_32x32x16_bf16(af, bf, acc, 0, 0, 0);
  }

  float* Pr = P + (size_t)blockIdx.y * 32 * N + c0 + nr;
#pragma unroll
  for (int r = 0; r < 16; r++) {
    int row = (r & 3) + 8 * (r >> 2) + 4 * lh;
    Pr[(size_t)row * N] = acc[r];
  }
}

// ---------------- MFMA M=32 weight-streaming GEMM (2-bank body) — small GEMMs ----------------
__global__ __launch_bounds__(256, 5) void gemmw(const unsigned short* __restrict__ Abf,
                                                const float* __restrict__ W,
                                                float* __restrict__ P,
                                                int K, int N, int L, int l4sh) {
  __shared__ __align__(16) unsigned short As[32 * 512];
  const int t = threadIdx.x;
  const int k0 = blockIdx.y * L;
  const int L4 = L >> 2;
  const int swzm = 2 * L - 1;
  for (int idx = t; idx < (L << 3); idx += 256) {
    int row = idx >> l4sh, k4 = idx & (L4 - 1);
    ushort4 a4 = *(const ushort4*)&Abf[(size_t)row * K + k0 + k4 * 4];
    int off = (row * 2 * L + k4 * 8) ^ (((row & 7) << 4) & swzm);
    *(ushort4*)((char*)As + off) = a4;
  }
  __syncthreads();
  const int lane = t & 63, w = t >> 6;
  const int lrow = lane & 31, lh = lane >> 5;
  const int col = blockIdx.x * 128 + w * 32 + lrow;
  f32x16 acc0, acc1;
#pragma unroll
  for (int r = 0; r < 16; r++) { acc0[r] = 0.f; acc1[r] = 0.f; }
  const float* Wp = W + (size_t)(k0 + lh * 8) * N + col;
  const int aswz = ((lrow & 7) << 4) & swzm;
  const int abase = lrow * 2 * L + lh * 16;
  const int nks = L >> 4;
  int ks = 0;
  for (; ks + 1 < nks; ks += 2) {
    float wv0[8], wv1[8];
#pragma unroll
    for (int jj = 0; jj < 8; jj++) wv0[jj] = Wp[(size_t)(ks * 16 + jj) * N];
#pragma unroll
    for (int jj = 0; jj < 8; jj++) wv1[jj] = Wp[(size_t)(ks * 16 + 16 + jj) * N];
    uint4 b0, b1;
    b0.x = pk2bf(wv0[0], wv0[1]); b0.y = pk2bf(wv0[2], wv0[3]);
    b0.z = pk2bf(wv0[4], wv0[5]); b0.w = pk2bf(wv0[6], wv0[7]);
    b1.x = pk2bf(wv1[0], wv1[1]); b1.y = pk2bf(wv1[2], wv1[3]);
    b1.z = pk2bf(wv1[4], wv1[5]); b1.w = pk2bf(wv1[6], wv1[7]);
    bf16x8 af0 = *(const bf16x8*)((const char*)As + ((abase + ks * 32) ^ aswz));
    bf16x8 af1 = *(const bf16x8*)((const char*)As + ((abase + ks * 32 + 32) ^ aswz));
    acc0 = __builtin_amdgcn_mfma_f32_32x32x16_bf16(af0, *(const bf16x8*)&b0, acc0, 0, 0, 0);
    acc1 = __builtin_amdgcn_mfma_f32_32x32x16_bf16(af1, *(const bf16x8*)&b1, acc1, 0, 0, 0);
  }
  if (ks < nks) {
    float wv0[8];
#pragma unroll
    for (int jj = 0; jj < 8; jj++) wv0[jj] = Wp[(size_t)(ks * 16 + jj) * N];
    uint4 b0;
    b0.x = pk2bf(wv0[0], wv0[1]); b0.y = pk2bf(wv0[2], wv0[3]);
    b0.z = pk2bf(wv0[4], wv0[5]); b0.w = pk2bf(wv0[6], wv0[7]);
    bf16x8 af0 = *(const bf16x8*)((const char*)As + ((abase + ks * 32) ^ aswz));
    acc0 = __builtin_amdgcn_mfma_f32_32x32x16_bf16(af0, *(const bf16x8*)&b0, acc0, 0, 0, 0);
  }
  float* Pr = P + (size_t)blockIdx.y * 32 * N + col;
#pragma unroll
  for (int r = 0; r < 16; r++) {
    int row = (r & 3) + 8 * (r >> 2) + 4 * lh;
    Pr[(size_t)row * N] = acc0[r] + acc1[r];
  }
}

// ================= reduce partials + bias + act (+ bf16 copy) (+ fused final combine) =================
__global__ __launch_bounds__(256) void reduce_kernel(const float* __restrict__ P,
                                                     const float* __restrict__ bias,
                                                     float* __restrict__ dst,
                                                     unsigned short* __restrict__ dstbf,
                                                     int lnN, int KS, int act, int wbf,
                                                     const float* __restrict__ S,
                                                     const float* __restrict__ Ip,
                                                     float* __restrict__ out0, int comb) {
  const int idx = blockIdx.x * 256 + threadIdx.x;
  const int N = 1 << lnN;
  const int m = idx >> lnN, n = idx & (N - 1);
  float s = 0.f;
#pragma unroll 8
  for (int p = 0; p < KS; p++) s += P[((size_t)(p * 32 + m) << lnN) + n];
  s += bias[n];
  if (act == 1) s = fmaxf(s, 0.f);
  else if (act == 2) s = tanhf(s);
  dst[idx] = s;
  if (wbf) dstbf[idx] = f2bf(s);
  if (comb) out0[idx] = S[idx] + 0.1f * (Ip[idx] + s);
}

// ================= interaction core v6 (R9-proven): V via LDS, persistent-B =================
__global__ __launch_bounds__(512, 2) void inter6_kernel(const f16* __restrict__ Uh,
                                                        const f16* __restrict__ Vh,
                                                        const f16* __restrict__ W2h,
                                                        const float* __restrict__ bi2,
                                                        float* __restrict__ Hsum) {
  __shared__ __align__(16) f16 Bt[128 * 512]; // 128KB
  __shared__ __align__(16) f16 Vc[64 * 128];  // 16KB
  const int t = threadIdx.x;
  const int nq = blockIdx.x;

#pragma unroll
  for (int i = 0; i < 16; i++) {
    int idx = i * 512 + t;
    int n = idx >> 6, ch = idx & 63;
    f16x8 w8 = *(const f16x8*)&W2h[(size_t)(nq * 128 + n) * 512 + ch * 8];
    int off = (n * 1024 + ch * 16) ^ ((n & 15) << 4);
    *(f16x8*)((char*)Bt + off) = w8;
  }

  const int w = t >> 6, lane = t & 63;
  const int ii = w & 1, tg = w >> 1;
  const int lrow = lane & 31, lh = lane >> 5;
  const char* Btc = (const char*)Bt;
  const char* Vcc = (const char*)Vc;
  char* Vcw = (char*)Vc;

  int bofs[4], bswz[4];
#pragma unroll
  for (int nf = 0; nf < 4; nf++) {
    int nr = nf * 32 + lrow;
    bofs[nf] = nr * 1024 + lh * 16;
    bswz[nf] = (nr & 15) << 4;
  }
  const int vofs0 = lrow * 256;
  const int vswz0 = (lrow & 15) << 4;
  const int vofs1 = (lrow + 32) * 256;
  const int vswz1 = vswz0;

  const int b = blockIdx.y >> 1;

  for (int s = 0; s < 4; s++) {
    const int tid = blockIdx.y * 16 + tg * 4 + s;
    const int it = tid & 31;
    const f16* Ub = Uh + (size_t)(b * 64 + it * 2 + ii) * 512 + lh * 8;

    f32x16 acc[2][4];
#pragma unroll
    for (int mf = 0; mf < 2; mf++)
#pragma unroll
      for (int nf = 0; nf < 4; nf++)
#pragma unroll
        for (int r = 0; r < 16; r++) acc[mf][nf][r] = 0.f;

    for (int ch = 0; ch < 4; ch++) {
      const int kc = ch * 128;
      __syncthreads();
#pragma unroll
      for (int i = 0; i < 2; i++) {
        int idx = i * 512 + t;
        int row = idx >> 4, c8 = idx & 15;
        f16x8 w8 = *(const f16x8*)&Vh[(size_t)(b * 64 + row) * 512 + kc + c8 * 8];
        *(f16x8*)(Vcw + ((row * 256 + c8 * 16) ^ ((row & 15) << 4))) = w8;
      }
      __syncthreads();
#pragma unroll
      for (int k16 = 0; k16 < 8; k16++) {
        const int kb2 = k16 * 32 + lh * 16;
        f16x8 v0 = *(const f16x8*)(Vcc + ((vofs0 + kb2) ^ vswz0));
        f16x8 v1 = *(const f16x8*)(Vcc + ((vofs1 + kb2) ^ vswz1));
        f16x8 u0 = *(const f16x8*)(Ub + kc + k16 * 16);
        f16x8 a0 = relu8(v0 + u0);
        f16x8 a1 = relu8(v1 + u0);
#pragma unroll
        for (int nf = 0; nf < 4; nf++) {
          f16x8 bfr = *(const f16x8*)(Btc + ((bofs[nf] + (kc + k16 * 16) * 2) ^ bswz[nf]));
          acc[0][nf] = __builtin_amdgcn_mfma_f32_32x32x16_f16(a0, bfr, acc[0][nf], 0, 0, 0);
          acc[1][nf] = __builtin_amdgcn_mfma_f32_32x32x16_f16(a1, bfr, acc[1][nf], 0, 0, 0);
        }
      }
    }

    const int iglob = it * 2 + ii;
    const int mf_d = iglob >> 5;
    const int rd = iglob & 31;
    const int lh_d = (rd >> 2) & 1;
    const int r_d = (rd & 3) + 4 * (rd >> 3);
#pragma unroll
    for (int nf = 0; nf < 4; nf++) {
      const int col = nq * 128 + nf * 32 + lrow;
      const float b2 = bi2[col];
      float ssum = 0.f;
#pragma unroll
      for (int mf = 0; mf < 2; mf++)
#pragma unroll
        for (int r = 0; r < 16; r++) {
          float x = fmaxf(acc[mf][nf][r] + b2, 0.f);
          if (mf == mf_d && r == r_d && lh == lh_d) x = 0.f;
          ssum += x;
        }
      ssum += __shfl_xor(ssum, 32);
      if (lh == 0) Hsum[(size_t)(b * 64 + iglob) * 512 + col] = ssum;
    }
  }
}

// ---------------- interactions = (Hsum/63) @ Wi3 + bi3, 256 blocks ----------------
__global__ __launch_bounds__(256) void k3_kernel(const float* __restrict__ Hsum,
                                                 const float* __restrict__ Wi3,
                                                 const float* __restrict__ bi3,
                                                 float* __restrict__ inter) {
  __shared__ float st[512][10];
  const int t = threadIdx.x;
  const int row0 = blockIdx.x * 8;
  for (int idx = t; idx < 4096; idx += 256) {
    int r = idx >> 9, k = idx & 511;
    st[k][r] = Hsum[(row0 + r) * 512 + k] * (1.0f / 63.0f);
  }
  __syncthreads();
  const int c = t & 63;
  const int rg = t >> 6;
  float a0[2] = {0.f, 0.f}, a1[2] = {0.f, 0.f};
#pragma unroll 4
  for (int k = 0; k < 512; k++) {
    float w0 = Wi3[k * 128 + c];
    float w1 = Wi3[k * 128 + 64 + c];
    float2 h = *(const float2*)&st[k][rg * 2];
    a0[0] += h.x * w0; a0[1] += h.y * w0;
    a1[0] += h.x * w1; a1[1] += h.y * w1;
  }
  float b0 = bi3[c], b1 = bi3[64 + c];
#pragma unroll
  for (int r = 0; r < 2; r++) {
    inter[(row0 + rg * 2 + r) * 128 + c]      = a0[r] + b0;
    inter[(row0 + rg * 2 + r) * 128 + 64 + c] = a1[r] + b1;
  }
}

extern "C" void kernel_launch(void* const* d_in, const int* in_sizes, int n_in,
                              void* d_out, int out_size, void* d_ws, size_t ws_size,
                              hipStream_t stream) {
  const float* states = (const float*)d_in[0];
  const float* Wq  = (const float*)d_in[2];
  const float* bq  = (const float*)d_in[3];
  const float* Wi1 = (const float*)d_in[4];
  const float* bi1 = (const float*)d_in[5];
  const float* Wi2 = (const float*)d_in[6];
  const float* bi2 = (const float*)d_in[7];
  const float* Wi3 = (const float*)d_in[8];
  const float* bi3 = (const float*)d_in[9];
  const float* Wc1 = (const float*)d_in[10];
  const float* bc1 = (const float*)d_in[11];
  const float* Wc2 = (const float*)d_in[12];
  const float* bc2 = (const float*)d_in[13];
  const float* Wc3 = (const float*)d_in[14];
  const float* bc3 = (const float*)d_in[15];

  float* out   = (float*)d_out;
  float* out0  = out;            // coordinated_states (B,A,D)
  float* qf    = out + 262144;   // quantum_features (B,F)
  float* inter = out + 524288;   // interactions (B,A,D)
  float* coord = out + 786432;   // coordination (B,A,D)

  char* ws = (char*)d_ws;
  float*          P    = (float*)(ws);                                   // 16MB partials
  f16*            Uh   = (f16*)(ws + ((size_t)16 << 20));                // 2MB
  f16*            Vh   = (f16*)(ws + ((size_t)19 << 20));                // 2MB
  f16*            W2h  = (f16*)(ws + ((size_t)22 << 20));                // 0.5MB
  float*          Hsum = (float*)(ws + ((size_t)23 << 20));              // 4MB
  unsigned short* Sbf  = (unsigned short*)(ws + ((size_t)27 << 20));     // 0.5MB
  unsigned short* qfbf = (unsigned short*)(ws + ((size_t)28 << 20));     // 0.5MB
  float*          c1   = (float*)(ws + ((size_t)29 << 20));              // 64KB
  float*          c2   = (float*)(ws + ((size_t)29 << 20) + (1 << 16));  // 64KB
  unsigned short* c1bf = (unsigned short*)(ws + ((size_t)29 << 20) + (2 << 16)); // 32KB
  unsigned short* c2bf = (unsigned short*)(ws + ((size_t)29 << 20) + (3 << 16)); // 32KB

  // fused prep: tobf + w2h + uvh
  prep_kernel<<<768, 256, 0, stream>>>(states, Wi2, Wi1, bi1, Sbf, W2h, Uh, Vh);

  // quantum features: qf = tanh(states @ Wq + bq) — LDS-staged-B burst gemm, KS=16
  gemmw3<<<dim3(64, 16), 256, 0, stream>>>(Sbf, Wq, P, 8192, 8192);
  reduce_kernel<<<1024, 256, 0, stream>>>(P, bq, qf, qfbf, 13, 16, 2, 1,
                                          nullptr, nullptr, nullptr, 0);

  // interactions
  inter6_kernel<<<dim3(4, 64), 512, 0, stream>>>(Uh, Vh, W2h, bi2, Hsum);
  k3_kernel<<<256, 256, 0, stream>>>(Hsum, Wi3, bi3, inter);

  // coordination chain
  gemmw<<<dim3(4, 64), 256, 0, stream>>>(qfbf, Wc1, P, 8192, 512, 128, 5);
  reduce_kernel<<<64, 256, 0, stream>>>(P, bc1, c1, c1bf, 9, 64, 1, 1,
                                        nullptr, nullptr, nullptr, 0);
  gemmw<<<dim3(4, 32), 256, 0, stream>>>(c1bf, Wc2, P, 512, 512, 16, 2);
  reduce_kernel<<<64, 256, 0, stream>>>(P, bc2, c2, c2bf, 9, 32, 1, 1,
                                        nullptr, nullptr, nullptr, 0);

  // coord = c2 @ Wc3 + bc3 + fused final combine
  gemmw<<<dim3(64, 8), 256, 0, stream>>>(c2bf, Wc3, P, 512, 8192, 64, 4);
  reduce_kernel<<<1024, 256, 0, stream>>>(P, bc3, coord, nullptr, 13, 8, 0, 0,
                                          states, inter, out0, 1);
}